// Round 4
// baseline (49.022 us; speedup 1.0000x reference)
//
#include <hip/hip_runtime.h>

#define PS     25
#define PADR   12
#define EPSV   (1.0f/255.0f)
#define WW     512
#define HH     512
#define NB     16
#define TS     16            // output rows per wave
#define INV625 (1.0f/625.0f)

__device__ __forceinline__ int reflectI(int i, int n) {
    if (i < 0)  i = -i;
    if (i >= n) i = 2 * n - 2 - i;
    return i;
}

__device__ __forceinline__ float fastrcp(float x) {
    float y;
    asm("v_rcp_f32 %0, %1" : "=v"(y) : "v"(x));
    return y;
}

// load 4 raw rgb values (reflect-handled cols) for row ry starting at col c0
__device__ __forceinline__ void loadRGB(const float* __restrict__ pR,
                                        const float* __restrict__ pG,
                                        const float* __restrict__ pB,
                                        int ry, int c0, bool vecOK,
                                        float r[4], float g[4], float b[4])
{
    const size_t ro = (size_t)ry * WW;
    if (vecOK) {
        float4 a = *(const float4*)(pR + ro + c0);
        float4 c = *(const float4*)(pG + ro + c0);
        float4 d = *(const float4*)(pB + ro + c0);
        r[0]=a.x; r[1]=a.y; r[2]=a.z; r[3]=a.w;
        g[0]=c.x; g[1]=c.y; g[2]=c.z; g[3]=c.w;
        b[0]=d.x; b[1]=d.y; b[2]=d.z; b[3]=d.w;
    } else {
#pragma unroll
        for (int j = 0; j < 4; ++j) {
            int cc = reflectI(c0 + j, WW);
            r[j] = pR[ro + cc];
            g[j] = pG[ro + cc];
            b[j] = pB[ro + cc];
        }
    }
}

__device__ __forceinline__ void computeMS(const float* __restrict__ pR,
                                          const float* __restrict__ pG,
                                          const float* __restrict__ pB,
                                          int ry, int c0, bool vecOK,
                                          float m[4], float s[4])
{
    float r[4], g[4], b[4];
    loadRGB(pR, pG, pB, ry, c0, vecOK, r, g, b);
#pragma unroll
    for (int j = 0; j < 4; ++j) {
        m[j] = (r[j] + g[j] + b[j]) * (1.0f/3.0f);
        s[j] = fmaf(r[j], r[j], fmaf(g[j], g[j], b[j]*b[j])) * (1.0f/3.0f);
    }
}

// 1 wave (64 threads) per block; each thread owns 4 consecutive columns.
// Vertical 25-tap = register running sum (subtract re-reads from LLC).
// Horizontal 25-tap via per-block LDS row buffer; NO __syncthreads anywhere.
__global__ __launch_bounds__(64)
void fused_stream(const float* __restrict__ img, float* __restrict__ out)
{
    const int t  = threadIdx.x;
    const int xt = blockIdx.x;          // 0..2  output cols {0,232,464}
    const int ys = blockIdx.y;          // 0..31 row strip
    const int b  = blockIdx.z;

    const int x0_out  = xt * 232;
    const int out_w   = (xt == 2) ? 48 : 232;
    const int need_w  = out_w + 2 * PADR;      // 256,256,72
    const int x0_load = x0_out - PADR;

    const int  c0      = x0_load + 4 * t;      // first raw col of this thread (halo frame)
    const int  cs0     = c0 + PADR;            // first OUTPUT col of this thread
    const bool activeL = (4 * t < need_w);
    const bool doOut   = (4 * t < out_w);
    const bool vecOK   = (c0 >= 0) && (c0 + 3 < WW);

    if (!activeL) return;                      // safe: no barriers in kernel

    __shared__ float vmRow[260];
    __shared__ float vsRow[260];

    const size_t plane = (size_t)WW * HH;
    const float* pR = img + (size_t)b * 3 * plane;
    const float* pG = pR + plane;
    const float* pB = pR + 2 * plane;

    const int r0 = ys * TS;

    // ---- prologue: vertical sums over window of first output row ----
    float vm[4] = {0,0,0,0}, vs[4] = {0,0,0,0};
    for (int k = -PADR; k <= PADR; ++k) {
        float m[4], s[4];
        computeMS(pR, pG, pB, reflectI(r0 + k, HH), c0, vecOK, m, s);
#pragma unroll
        for (int j = 0; j < 4; ++j) { vm[j] += m[j]; vs[j] += s[j]; }
    }

    // ---- steady loop over output rows ----
    for (int yo = r0; yo < r0 + TS; ++yo) {
        // incoming row (fresh, HBM) and outgoing row (LLC re-read)
        float mi[4], si[4], mo[4], so[4];
        computeMS(pR, pG, pB, reflectI(yo + PADR + 1, HH), c0, vecOK, mi, si);
        computeMS(pR, pG, pB, reflectI(yo - PADR,     HH), c0, vecOK, mo, so);

        // publish vertical sums for this row
        *(float4*)&vmRow[4*t] = make_float4(vm[0], vm[1], vm[2], vm[3]);
        *(float4*)&vsRow[4*t] = make_float4(vs[0], vs[1], vs[2], vs[3]);

        if (doOut) {
            // saturation at this thread's OUTPUT columns (cs0..cs0+3),
            // always in-bounds and 16B-aligned for doOut lanes
            const size_t ro = (size_t)yo * WW;
            float4 ra = *(const float4*)(pR + ro + cs0);
            float4 ga = *(const float4*)(pG + ro + cs0);
            float4 ba = *(const float4*)(pB + ro + cs0);
            float r[4] = {ra.x, ra.y, ra.z, ra.w};
            float g[4] = {ga.x, ga.y, ga.z, ga.w};
            float bb[4] = {ba.x, ba.y, ba.z, ba.w};
            float sat[4];
#pragma unroll
            for (int j = 0; j < 4; ++j) {
                float mx = fmaxf(r[j], fmaxf(g[j], bb[j]));
                float mn = fminf(r[j], fminf(g[j], bb[j]));
                sat[j] = (mx - mn + EPSV) * fastrcp(mx + EPSV);
            }

            // read 28-float windows (7 x b128 per array), in-wave ordering
            float wm[28], ws[28];
#pragma unroll
            for (int i = 0; i < 7; ++i) {
                float4 a = *(const float4*)&vmRow[4*t + 4*i];
                float4 c = *(const float4*)&vsRow[4*t + 4*i];
                wm[4*i]=a.x; wm[4*i+1]=a.y; wm[4*i+2]=a.z; wm[4*i+3]=a.w;
                ws[4*i]=c.x; ws[4*i+1]=c.y; ws[4*i+2]=c.z; ws[4*i+3]=c.w;
            }
            float hm = 0.f, hs = 0.f;
#pragma unroll
            for (int i = 0; i < PS; ++i) { hm += wm[i]; hs += ws[i]; }

            float sc[4];
#pragma unroll
            for (int j = 0; j < 4; ++j) {
                if (j > 0) {
                    hm += wm[PS - 1 + j] - wm[j - 1];
                    hs += ws[PS - 1 + j] - ws[j - 1];
                }
                float mean     = hm * INV625;
                float msq      = hs * INV625;
                float contrast = fmaf(-mean, mean, msq);
                float expo     = fabsf(mean - 0.5f) + EPSV;
                sc[j] = sat[j] * contrast * fastrcp(expo);
            }
            float* orow = out + ((size_t)b * HH + yo) * WW + x0_out + 4*t;
            *(float4*)orow = make_float4(sc[0], sc[1], sc[2], sc[3]);
        }

        // slide the vertical window
#pragma unroll
        for (int j = 0; j < 4; ++j) {
            vm[j] += mi[j] - mo[j];
            vs[j] += si[j] - so[j];
        }
    }
}

extern "C" void kernel_launch(void* const* d_in, const int* in_sizes, int n_in,
                              void* d_out, int out_size, void* d_ws, size_t ws_size,
                              hipStream_t stream)
{
    const float* img = (const float*)d_in[0];
    float* out = (float*)d_out;

    dim3 grid(3, HH / TS, NB);     // 3 x-tiles, 32 row strips, 16 images
    fused_stream<<<grid, 64, 0, stream>>>(img, out);
}